// Round 12
// baseline (110.312 us; speedup 1.0000x reference)
//
#include <hip/hip_runtime.h>

#define N_WORDS 16384
#define TSTEPS 16
#define NCHARS 128
#define HIDDEN 128
#define HSTRIDE 136   // shorts per LDS row: 16B-aligned, 2-way-bank (free)

typedef float f32x4 __attribute__((ext_vector_type(4)));
typedef short s16x8 __attribute__((ext_vector_type(8)));
typedef int   i32x4 __attribute__((ext_vector_type(4)));
typedef unsigned int u32;

// ws layout (bytes)
#define WS_IDXW  0                  // 256 KB : idx_w bytes [word][t]
#define WS_IDXS  (256 * 1024)       // 256 KB : idx_s bytes [t][slot]
#define WS_XPROJ (512 * 1024)       // 512 KB : xproj f32x4 [dir][char][unit] (i,f,g,o), log2e-scaled
#define WS_PERM  (1024 * 1024)      // 64 KB  : perm (slot -> word)
#define WS_LEN   (1088 * 1024)      // 64 KB  : len_perm (slot -> len)
#define WS_CTRL  (1152 * 1024)      // 192 B  : ghist[16] | pad | gcursor[16]
#define WS_WFRAG (1184 * 1024)      // 256 KB : W_hh bf16 MFMA B-fragments (scaled)

#define NL2E  (-1.44269504089f)     // -log2(e): sigmoid rows (i,f,o)
#define N2L2E (-2.88539008178f)     // -2*log2(e): tanh rows (g)

#define NB_EXT 32768                // extract blocks in k_front

static __device__ __forceinline__ short f2bf(float f) {
  unsigned u = __builtin_bit_cast(unsigned, f);
  u += 0x7FFFu + ((u >> 16) & 1u);
  return (short)(u >> 16);
}

// ---------------------------------------------------------------------------
// fused front kernel:
//  [0, NB_EXT)          : one-hot -> char byte, WORD-indexed idx_w[n][t]
//  [NB_EXT, +128)       : xproj f32x4 [dir][char][unit] (gates packed), log2e-scaled
//  [NB_EXT+128, +192)   : W_hh -> bf16 B-fragments, log2e-scaled
//  [NB_EXT+192, +256)   : length histogram (descending bins)
// ---------------------------------------------------------------------------
__global__ __launch_bounds__(256) void k_front(
    const float* __restrict__ x, const int* __restrict__ lengths,
    const float* __restrict__ Wihf, const float* __restrict__ bif, const float* __restrict__ bhf,
    const float* __restrict__ Wihb, const float* __restrict__ bib, const float* __restrict__ bhb,
    const float* __restrict__ Whhf, const float* __restrict__ Whhb,
    f32x4* __restrict__ xp4, s16x8* __restrict__ wfrag,
    unsigned char* __restrict__ idx_w, int* __restrict__ ghist) {
  if (blockIdx.x < NB_EXT) {
    const int wpair = blockIdx.x * 4 + (threadIdx.x >> 6);
    const int lane  = threadIdx.x & 63;
    const int half  = lane >> 5, sub = lane & 31;
    const int row   = wpair * 2 + half;               // row = n*16 + t
    const int n = row >> 4, t = row & 15;
    const int len = lengths[n];
    int myv = -1;
    if (t < len) {
      const f32x4 v = *(const f32x4*)(x + (size_t)row * NCHARS + sub * 4);
      int loc = -1;
      loc = (v[0] > 0.5f) ? 0 : loc;
      loc = (v[1] > 0.5f) ? 1 : loc;
      loc = (v[2] > 0.5f) ? 2 : loc;
      loc = (v[3] > 0.5f) ? 3 : loc;
      if (loc >= 0) myv = sub * 4 + loc;
    }
    const unsigned long long ball = __ballot(myv >= 0);
    const unsigned long long mym = half ? (ball >> 32) : (ball & 0xffffffffull);
    const int wn = __ffsll(mym) - 1 + (half << 5);
    const int c = __shfl(myv, wn);
    if (sub == 0 && t < len)
      idx_w[n * 16 + t] = (unsigned char)c;
  } else if (blockIdx.x < NB_EXT + 128) {
    const int gid = (blockIdx.x - NB_EXT) * 256 + threadIdx.x;  // [0, 32768)
    const int u = gid & 127;
    const int c = (gid >> 7) & 127;
    const int d = gid >> 14;
    const float* W  = d ? Wihb : Wihf;
    const float* bi = d ? bib : bif;
    const float* bh = d ? bhb : bhf;
    f32x4 v;
#pragma unroll
    for (int g = 0; g < 4; ++g) {
      const int row = g * HIDDEN + u;
      const float s = (g == 2) ? N2L2E : NL2E;
      v[g] = s * (W[row * NCHARS + c] + bi[row] + bh[row]);
    }
    xp4[gid] = v;
  } else if (blockIdx.x < NB_EXT + 192) {
    const int gid = (blockIdx.x - NB_EXT - 128) * 256 + threadIdx.x;  // [0, 16384)
    const int f    = gid & 15;          // frag: g = f>>2, kt = f&3
    const int lane = (gid >> 4) & 63;
    const int ug   = (gid >> 10) & 7;
    const int d    = gid >> 13;
    const float* W = d ? Whhb : Whhf;
    const int l15 = lane & 15, q = lane >> 4;
    const int gt  = f >> 2;
    const float s = (gt == 2) ? N2L2E : NL2E;
    const int row = gt * HIDDEN + ug * 16 + l15;
    const int k0  = (f & 3) * 32 + q * 4;
    const f32x4 lo = *(const f32x4*)(W + row * HIDDEN + k0);
    const f32x4 hi = *(const f32x4*)(W + row * HIDDEN + k0 + 16);
    s16x8 o;
    o[0] = f2bf(s * lo[0]); o[1] = f2bf(s * lo[1]); o[2] = f2bf(s * lo[2]); o[3] = f2bf(s * lo[3]);
    o[4] = f2bf(s * hi[0]); o[5] = f2bf(s * hi[1]); o[6] = f2bf(s * hi[2]); o[7] = f2bf(s * hi[3]);
    wfrag[((d * 8 + ug) * 16 + f) * 64 + lane] = o;
  } else {
    __shared__ int lh[16];
    if (threadIdx.x < 16) lh[threadIdx.x] = 0;
    __syncthreads();
    const int gid = (blockIdx.x - NB_EXT - 192) * 256 + threadIdx.x;
    const int len = lengths[gid];
    atomicAdd(&lh[16 - len], 1);
    __syncthreads();
    if (threadIdx.x < 16) atomicAdd(&ghist[threadIdx.x], lh[threadIdx.x]);
  }
}

// ---------------------------------------------------------------------------
// place (counting-sort by descending length, inline scan) + scatter of the
// char table to [t][slot] layout for the LSTM's one-u32-per-step loads.
// Any within-bin permutation gives bit-identical per-word output.
// ---------------------------------------------------------------------------
__global__ __launch_bounds__(256) void k_place(const int* __restrict__ lengths,
                                               const int* __restrict__ ghist,
                                               int* __restrict__ gcursor,
                                               int* __restrict__ perm,
                                               int* __restrict__ len_perm,
                                               const unsigned char* __restrict__ idx_w,
                                               unsigned char* __restrict__ idx_s) {
  __shared__ int wcnt[4][16];
  __shared__ int bbase[16];
  const int tid = threadIdx.x, w = tid >> 6, lane = tid & 63;
  const int gid = blockIdx.x * 256 + tid;
  const int len = lengths[gid], bin = 16 - len;
  const unsigned long long lmask = (1ull << lane) - 1ull;
  int rankw = 0;
#pragma unroll
  for (int b = 0; b < 16; ++b) {
    const unsigned long long m = __ballot(bin == b);
    if (bin == b) rankw = __popcll(m & lmask);
    if (lane == b) wcnt[w][b] = __popcll(m);
  }
  __syncthreads();
  if (tid < 16) {
    int s = 0;
    for (int b = 0; b < tid; ++b) s += ghist[b];      // exclusive scan
    const int tot = wcnt[0][tid] + wcnt[1][tid] + wcnt[2][tid] + wcnt[3][tid];
    bbase[tid] = s + atomicAdd(&gcursor[tid], tot);
  }
  __syncthreads();
  int rank = rankw;
  for (int w2 = 0; w2 < w; ++w2) rank += wcnt[w2][bin];
  const int slot = bbase[bin] + rank;
  perm[slot] = gid;
  len_perm[slot] = len;
  const i32x4 w4 = *(const i32x4*)(idx_w + gid * 16);
#pragma unroll
  for (int t = 0; t < 16; ++t)
    idx_s[t * N_WORDS + slot] = (unsigned char)((((u32)w4[t >> 2]) >> ((t & 3) * 8)) & 255);
}

// ---------------------------------------------------------------------------
// gather next step's gate pre-activations: 4 x dwordx4, scattered per-r into
// the (dead) acc registers so the transient xv is only 4 VGPRs.
// ---------------------------------------------------------------------------
static __device__ __forceinline__ void gather4(const f32x4* __restrict__ xpd4,
                                               u32 cc, f32x4 acc[4]) {
#pragma unroll
  for (int r = 0; r < 4; ++r) {
    const f32x4 xv = xpd4[((cc >> (8 * r)) & 127) << 7];
    acc[0][r] = xv[0];
    acc[1][r] = xv[1];
    acc[2][r] = xv[2];
    acc[3][r] = xv[3];
  }
}

// one LSTM step; UNIF = tile is length-uniform (no masking needed).
template<bool UNIF>
static __device__ __forceinline__ void lstm_step(
    int t, int maxlen, int dir, const i32x4& lenv,
    const f32x4* __restrict__ xpd4, const unsigned char* __restrict__ idx_s,
    int wbase, u32& cc, f32x4 acc[4], f32x4& h, f32x4& cs,
    const s16x8* __restrict__ Bf, short (*hbuf)[16 * HSTRIDE],
    int l15, int q, int pos) {
  if (t > 0) {
    const short* __restrict__ hr = hbuf[t & 1] + l15 * HSTRIDE;
    __builtin_amdgcn_s_setprio(1);
#pragma unroll
    for (int kt = 0; kt < 4; ++kt) {
      const s16x8 a = *(const s16x8*)(hr + kt * 32 + q * 8);
#pragma unroll
      for (int g = 0; g < 4; ++g)
        acc[g] = __builtin_amdgcn_mfma_f32_16x16x32_bf16(a, Bf[g * 4 + kt], acc[g], 0, 0, 0);
    }
    __builtin_amdgcn_s_setprio(0);
  }

  const int te = dir ? (maxlen - 1 - t) : t;     // folded away when UNIF
#pragma unroll
  for (int r = 0; r < 4; ++r) {
    const float gi = __builtin_amdgcn_rcpf(1.0f + __builtin_amdgcn_exp2f(acc[0][r]));
    const float gf = __builtin_amdgcn_rcpf(1.0f + __builtin_amdgcn_exp2f(acc[1][r]));
    const float gg = 2.0f * __builtin_amdgcn_rcpf(1.0f + __builtin_amdgcn_exp2f(acc[2][r])) - 1.0f;
    const float go = __builtin_amdgcn_rcpf(1.0f + __builtin_amdgcn_exp2f(acc[3][r]));
    const float cn = gf * cs[r] + gi * gg;
    const float hn = go * (2.0f * __builtin_amdgcn_rcpf(1.0f + __builtin_amdgcn_exp2f(cn * N2L2E)) - 1.0f);
    if (UNIF) {
      cs[r] = cn; h[r] = hn;
    } else {
      const bool mk = (te < lenv[r]);
      cs[r] = mk ? cn : cs[r];
      h[r]  = mk ? hn : h[r];
    }
  }

  if (t + 1 < maxlen) {
    // pack h -> bf16 pairs (RNE) and write the h-exchange rows
    u32 pk01, pk23;
    asm("v_cvt_pk_bf16_f32 %0, %1, %2" : "=v"(pk01) : "v"(h[0]), "v"(h[1]));
    asm("v_cvt_pk_bf16_f32 %0, %1, %2" : "=v"(pk23) : "v"(h[2]), "v"(h[3]));
    short* __restrict__ hw = hbuf[(t & 1) ^ 1];
    hw[(q * 4 + 0) * HSTRIDE + pos] = (short)pk01;
    hw[(q * 4 + 1) * HSTRIDE + pos] = (short)(pk01 >> 16);
    hw[(q * 4 + 2) * HSTRIDE + pos] = (short)pk23;
    hw[(q * 4 + 3) * HSTRIDE + pos] = (short)(pk23 >> 16);

    // issue NEXT step's gathers into the now-dead acc regs (stay in flight
    // across the raw barrier; no vmcnt drain).
    gather4(xpd4, cc, acc);
    if (t + 2 < maxlen) {
      const int t3 = dir ? (maxlen - 3 - t) : (t + 2);
      cc = *(const u32*)(idx_s + t3 * N_WORDS + wbase);
    }
  }

  asm volatile("s_waitcnt lgkmcnt(0)" ::: "memory");
  __builtin_amdgcn_s_barrier();
}

// ---------------------------------------------------------------------------
// recurrence, PERSISTENT: 512 blocks x 512 thr; [0,256)=dir0, [256,512)=dir1.
// Block b handles tiles {b, 511-b, 512+b, 1023-b} (descending sort -> LPT).
// W_hh frags resident (64 AGPRs). Uniform-length tiles (~98% after the sort)
// take a mask-free fast path. t=0 skips ds_read+MFMA (h=0); final step skips
// the h store.
//   A-frag: lane l reads k = kt*32 + (l>>4)*4 + j (j<4), +16 for j>=4
//   C/D   : lane l, reg r -> row m=(l>>4)*4+r, col n=l&15
// Pre-activations pre-scaled by -log2e (i,f,o) / -2log2e (g):
//   sigmoid(z) = rcp(1+exp2(zs)), tanh(z) = 2*rcp(1+exp2(zs)) - 1.
// ---------------------------------------------------------------------------
__global__ __launch_bounds__(512, 4) void k_lstm(
    const f32x4* __restrict__ xp4, const unsigned char* __restrict__ idx_s,
    const int* __restrict__ perm, const int* __restrict__ len_perm,
    const s16x8* __restrict__ wfrag, float* __restrict__ out) {
  const int dir = blockIdx.x >> 8;
  const int db  = blockIdx.x & 255;
  const int ug  = threadIdx.x >> 6;
  const int lane = threadIdx.x & 63;
  const int l15 = lane & 15, q = lane >> 4;
  const int u = ug * 16 + l15;

  s16x8 Bf[16];                                  // [g*4+kt], lives in AGPRs
  const s16x8* wb = wfrag + (dir * 8 + ug) * (16 * 64) + lane;
#pragma unroll
  for (int f = 0; f < 16; ++f) Bf[f] = wb[f * 64];

  __shared__ short hbuf[2][16 * HSTRIDE];
  const f32x4* __restrict__ xpd4 = xp4 + (dir << 14) + u;
  const int pos = (ug >> 1) * 32 + (l15 >> 2) * 8 + (ug & 1) * 4 + (l15 & 3);

#pragma unroll 1
  for (int p = 0; p < 4; ++p) {
    const int rank = (p == 0) ? db : (p == 1) ? (511 - db)
                   : (p == 2) ? (512 + db) : (1023 - db);
    const int n0 = rank << 4;
    const int wbase = n0 + q * 4;
    const i32x4 lenv = *(const i32x4*)(len_perm + wbase);
    const int maxlen = len_perm[n0];             // slot n0 = longest in tile
    const bool unif = __all((lenv[0] == maxlen) & (lenv[1] == maxlen) &
                            (lenv[2] == maxlen) & (lenv[3] == maxlen));
    f32x4 h = (f32x4)0.0f, cs = (f32x4)0.0f;

    // prologue: gather step-0 gates; prefetch step-1 chars
    u32 cc = *(const u32*)(idx_s + (dir ? (maxlen - 1) : 0) * N_WORDS + wbase);
    f32x4 acc[4];
    gather4(xpd4, cc, acc);
    if (maxlen > 1)
      cc = *(const u32*)(idx_s + (dir ? (maxlen - 2) : 1) * N_WORDS + wbase);

    if (unif) {
#pragma unroll 1
      for (int t = 0; t < maxlen; ++t)
        lstm_step<true>(t, maxlen, dir, lenv, xpd4, idx_s, wbase, cc, acc, h, cs,
                        Bf, hbuf, l15, q, pos);
    } else {
#pragma unroll 1
      for (int t = 0; t < maxlen; ++t)
        lstm_step<false>(t, maxlen, dir, lenv, xpd4, idx_s, wbase, cc, acc, h, cs,
                         Bf, hbuf, l15, q, pos);
    }

    const i32x4 pw = *(const i32x4*)(perm + wbase);
#pragma unroll
    for (int r = 0; r < 4; ++r)
      out[(size_t)pw[r] * 256 + dir * HIDDEN + u] = h[r];
  }
}

// ---------------------------------------------------------------------------
extern "C" void kernel_launch(void* const* d_in, const int* in_sizes, int n_in,
                              void* d_out, int out_size, void* d_ws, size_t ws_size,
                              hipStream_t stream) {
  const float* x      = (const float*)d_in[0];
  const int*   lens   = (const int*)d_in[1];
  const float* W_ih_f = (const float*)d_in[2];
  const float* W_hh_f = (const float*)d_in[3];
  const float* b_ih_f = (const float*)d_in[4];
  const float* b_hh_f = (const float*)d_in[5];
  const float* W_ih_b = (const float*)d_in[6];
  const float* W_hh_b = (const float*)d_in[7];
  const float* b_ih_b = (const float*)d_in[8];
  const float* b_hh_b = (const float*)d_in[9];
  float* out = (float*)d_out;

  unsigned char* idx_w = (unsigned char*)d_ws + WS_IDXW;
  unsigned char* idx_s = (unsigned char*)d_ws + WS_IDXS;
  f32x4* xp4     = (f32x4*)((char*)d_ws + WS_XPROJ);
  int*   perm    = (int*)((char*)d_ws + WS_PERM);
  int*   lenp    = (int*)((char*)d_ws + WS_LEN);
  int*   ghist   = (int*)((char*)d_ws + WS_CTRL);
  int*   gcursor = ghist + 32;
  s16x8* wfrag   = (s16x8*)((char*)d_ws + WS_WFRAG);

  hipMemsetAsync((char*)d_ws + WS_CTRL, 0, 192, stream);
  hipLaunchKernelGGL(k_front, dim3(NB_EXT + 256), dim3(256), 0, stream,
                     x, lens,
                     W_ih_f, b_ih_f, b_hh_f, W_ih_b, b_ih_b, b_hh_b,
                     W_hh_f, W_hh_b, xp4, wfrag, idx_w, ghist);
  hipLaunchKernelGGL(k_place, dim3(N_WORDS / 256), dim3(256), 0, stream,
                     lens, ghist, gcursor, perm, lenp, idx_w, idx_s);
  hipLaunchKernelGGL(k_lstm, dim3(512), dim3(512), 0, stream,
                     xp4, idx_s, perm, lenp, wfrag, out);
}

// Round 13
// 94.973 us; speedup vs baseline: 1.1615x; 1.1615x over previous
//
#include <hip/hip_runtime.h>

#define N_WORDS 16384
#define TSTEPS 16
#define NCHARS 128
#define HIDDEN 128
#define HSTRIDE 136   // shorts per LDS row: 16B-aligned, 2-way-bank (free)

typedef float f32x4 __attribute__((ext_vector_type(4)));
typedef short s16x8 __attribute__((ext_vector_type(8)));
typedef int   i32x4 __attribute__((ext_vector_type(4)));
typedef unsigned int u32;

// ws layout (bytes)
#define WS_IDXW  0                  // 256 KB : idx_w bytes [word][t]
#define WS_IDXS  (256 * 1024)       // 256 KB : idx_s bytes [t][slot]
#define WS_XPROJ (512 * 1024)       // 512 KB : xproj f32 [dir][char][gate][unit], log2e-scaled
#define WS_PERM  (1024 * 1024)      // 64 KB  : perm (slot -> word)
#define WS_LEN   (1088 * 1024)      // 64 KB  : len_perm (slot -> len)
#define WS_CTRL  (1152 * 1024)      // 192 B  : ghist[16] | pad | gcursor[16]
#define WS_WFRAG (1184 * 1024)      // 256 KB : W_hh bf16 MFMA B-fragments (scaled)

#define NL2E  (-1.44269504089f)     // -log2(e): sigmoid rows (i,f,o)
#define N2L2E (-2.88539008178f)     // -2*log2(e): tanh rows (g)

#define NB_EXT 32768                // extract blocks in k_front

static __device__ __forceinline__ short f2bf(float f) {
  unsigned u = __builtin_bit_cast(unsigned, f);
  u += 0x7FFFu + ((u >> 16) & 1u);
  return (short)(u >> 16);
}

// ---------------------------------------------------------------------------
// fused front kernel:
//  [0, NB_EXT)          : one-hot -> char byte, WORD-indexed idx_w[n][t]
//  [NB_EXT, +512)       : xproj f32 [dir][char][gate][unit], log2e-scaled
//  [NB_EXT+512, +576)   : W_hh -> bf16 B-fragments, log2e-scaled
//  [NB_EXT+576, +640)   : length histogram (descending bins)
// ---------------------------------------------------------------------------
__global__ __launch_bounds__(256) void k_front(
    const float* __restrict__ x, const int* __restrict__ lengths,
    const float* __restrict__ Wihf, const float* __restrict__ bif, const float* __restrict__ bhf,
    const float* __restrict__ Wihb, const float* __restrict__ bib, const float* __restrict__ bhb,
    const float* __restrict__ Whhf, const float* __restrict__ Whhb,
    float* __restrict__ xp, s16x8* __restrict__ wfrag,
    unsigned char* __restrict__ idx_w, int* __restrict__ ghist) {
  if (blockIdx.x < NB_EXT) {
    const int wpair = blockIdx.x * 4 + (threadIdx.x >> 6);
    const int lane  = threadIdx.x & 63;
    const int half  = lane >> 5, sub = lane & 31;
    const int row   = wpair * 2 + half;               // row = n*16 + t
    const int n = row >> 4, t = row & 15;
    const int len = lengths[n];
    int myv = -1;
    if (t < len) {
      const f32x4 v = *(const f32x4*)(x + (size_t)row * NCHARS + sub * 4);
      int loc = -1;
      loc = (v[0] > 0.5f) ? 0 : loc;
      loc = (v[1] > 0.5f) ? 1 : loc;
      loc = (v[2] > 0.5f) ? 2 : loc;
      loc = (v[3] > 0.5f) ? 3 : loc;
      if (loc >= 0) myv = sub * 4 + loc;
    }
    const unsigned long long ball = __ballot(myv >= 0);
    const unsigned long long mym = half ? (ball >> 32) : (ball & 0xffffffffull);
    const int wn = __ffsll(mym) - 1 + (half << 5);
    const int c = __shfl(myv, wn);
    if (sub == 0 && t < len)
      idx_w[n * 16 + t] = (unsigned char)c;
  } else if (blockIdx.x < NB_EXT + 512) {
    const int gid = (blockIdx.x - NB_EXT) * 256 + threadIdx.x;  // [0, 131072)
    const int u = gid & 127;
    const int g = (gid >> 7) & 3;
    const int c = (gid >> 9) & 127;
    const int d = gid >> 16;
    const float* W  = d ? Wihb : Wihf;
    const float* bi = d ? bib : bif;
    const float* bh = d ? bhb : bhf;
    const int row = g * HIDDEN + u;
    const float s = (g == 2) ? N2L2E : NL2E;
    xp[gid] = s * (W[row * NCHARS + c] + bi[row] + bh[row]);
  } else if (blockIdx.x < NB_EXT + 576) {
    const int gid = (blockIdx.x - NB_EXT - 512) * 256 + threadIdx.x;  // [0, 16384)
    const int f    = gid & 15;          // frag: g = f>>2, kt = f&3
    const int lane = (gid >> 4) & 63;
    const int ug   = (gid >> 10) & 7;
    const int d    = gid >> 13;
    const float* W = d ? Whhb : Whhf;
    const int l15 = lane & 15, q = lane >> 4;
    const int gt  = f >> 2;
    const float s = (gt == 2) ? N2L2E : NL2E;
    const int row = gt * HIDDEN + ug * 16 + l15;
    const int k0  = (f & 3) * 32 + q * 4;
    const f32x4 lo = *(const f32x4*)(W + row * HIDDEN + k0);
    const f32x4 hi = *(const f32x4*)(W + row * HIDDEN + k0 + 16);
    s16x8 o;
    o[0] = f2bf(s * lo[0]); o[1] = f2bf(s * lo[1]); o[2] = f2bf(s * lo[2]); o[3] = f2bf(s * lo[3]);
    o[4] = f2bf(s * hi[0]); o[5] = f2bf(s * hi[1]); o[6] = f2bf(s * hi[2]); o[7] = f2bf(s * hi[3]);
    wfrag[((d * 8 + ug) * 16 + f) * 64 + lane] = o;
  } else {
    __shared__ int lh[16];
    if (threadIdx.x < 16) lh[threadIdx.x] = 0;
    __syncthreads();
    const int gid = (blockIdx.x - NB_EXT - 576) * 256 + threadIdx.x;
    const int len = lengths[gid];
    atomicAdd(&lh[16 - len], 1);
    __syncthreads();
    if (threadIdx.x < 16) atomicAdd(&ghist[threadIdx.x], lh[threadIdx.x]);
  }
}

// ---------------------------------------------------------------------------
// place (counting-sort by descending length, inline scan) + scatter of the
// char table to [t][slot] layout for the LSTM's one-u32-per-step loads.
// Any within-bin permutation gives bit-identical per-word output.
// ---------------------------------------------------------------------------
__global__ __launch_bounds__(256) void k_place(const int* __restrict__ lengths,
                                               const int* __restrict__ ghist,
                                               int* __restrict__ gcursor,
                                               int* __restrict__ perm,
                                               int* __restrict__ len_perm,
                                               const unsigned char* __restrict__ idx_w,
                                               unsigned char* __restrict__ idx_s) {
  __shared__ int wcnt[4][16];
  __shared__ int bbase[16];
  const int tid = threadIdx.x, w = tid >> 6, lane = tid & 63;
  const int gid = blockIdx.x * 256 + tid;
  const int len = lengths[gid], bin = 16 - len;
  const unsigned long long lmask = (1ull << lane) - 1ull;
  int rankw = 0;
#pragma unroll
  for (int b = 0; b < 16; ++b) {
    const unsigned long long m = __ballot(bin == b);
    if (bin == b) rankw = __popcll(m & lmask);
    if (lane == b) wcnt[w][b] = __popcll(m);
  }
  __syncthreads();
  if (tid < 16) {
    int s = 0;
    for (int b = 0; b < tid; ++b) s += ghist[b];      // exclusive scan
    const int tot = wcnt[0][tid] + wcnt[1][tid] + wcnt[2][tid] + wcnt[3][tid];
    bbase[tid] = s + atomicAdd(&gcursor[tid], tot);
  }
  __syncthreads();
  int rank = rankw;
  for (int w2 = 0; w2 < w; ++w2) rank += wcnt[w2][bin];
  const int slot = bbase[bin] + rank;
  perm[slot] = gid;
  len_perm[slot] = len;
  const i32x4 w4 = *(const i32x4*)(idx_w + gid * 16);
#pragma unroll
  for (int t = 0; t < 16; ++t)
    idx_s[t * N_WORDS + slot] = (unsigned char)((((u32)w4[t >> 2]) >> ((t & 3) * 8)) & 255);
}

// ---------------------------------------------------------------------------
// one LSTM step; UNIF = tile is length-uniform (no masking needed).
// Scalar xproj gathers straight into the MFMA C-operand (proven no-spill).
// ---------------------------------------------------------------------------
template<bool UNIF>
static __device__ __forceinline__ void lstm_step(
    int t, int maxlen, int dir, const i32x4& lenv,
    const float* __restrict__ xpd, const unsigned char* __restrict__ idx_s,
    int wbase, u32& cc, f32x4 acc[4], f32x4& h, f32x4& cs,
    const s16x8* __restrict__ Bf, short (*hbuf)[16 * HSTRIDE],
    int l15, int q, int pos) {
  if (t > 0) {
    const short* __restrict__ hr = hbuf[t & 1] + l15 * HSTRIDE;
    __builtin_amdgcn_s_setprio(1);
#pragma unroll
    for (int kt = 0; kt < 4; ++kt) {
      const s16x8 a = *(const s16x8*)(hr + kt * 32 + q * 8);
#pragma unroll
      for (int g = 0; g < 4; ++g)
        acc[g] = __builtin_amdgcn_mfma_f32_16x16x32_bf16(a, Bf[g * 4 + kt], acc[g], 0, 0, 0);
    }
    __builtin_amdgcn_s_setprio(0);
  }

  const int te = dir ? (maxlen - 1 - t) : t;     // folded away when UNIF
#pragma unroll
  for (int r = 0; r < 4; ++r) {
    const float gi = __builtin_amdgcn_rcpf(1.0f + __builtin_amdgcn_exp2f(acc[0][r]));
    const float gf = __builtin_amdgcn_rcpf(1.0f + __builtin_amdgcn_exp2f(acc[1][r]));
    const float gg = 2.0f * __builtin_amdgcn_rcpf(1.0f + __builtin_amdgcn_exp2f(acc[2][r])) - 1.0f;
    const float go = __builtin_amdgcn_rcpf(1.0f + __builtin_amdgcn_exp2f(acc[3][r]));
    const float cn = gf * cs[r] + gi * gg;
    const float hn = go * (2.0f * __builtin_amdgcn_rcpf(1.0f + __builtin_amdgcn_exp2f(cn * N2L2E)) - 1.0f);
    if (UNIF) {
      cs[r] = cn; h[r] = hn;
    } else {
      const bool mk = (te < lenv[r]);
      cs[r] = mk ? cn : cs[r];
      h[r]  = mk ? hn : h[r];
    }
  }

  if (t + 1 < maxlen) {
    // pack h -> bf16 pairs (RNE, same rounding as f2bf) and write exchange rows
    u32 pk01, pk23;
    asm("v_cvt_pk_bf16_f32 %0, %1, %2" : "=v"(pk01) : "v"(h[0]), "v"(h[1]));
    asm("v_cvt_pk_bf16_f32 %0, %1, %2" : "=v"(pk23) : "v"(h[2]), "v"(h[3]));
    short* __restrict__ hw = hbuf[(t & 1) ^ 1];
    hw[(q * 4 + 0) * HSTRIDE + pos] = (short)pk01;
    hw[(q * 4 + 1) * HSTRIDE + pos] = (short)(pk01 >> 16);
    hw[(q * 4 + 2) * HSTRIDE + pos] = (short)pk23;
    hw[(q * 4 + 3) * HSTRIDE + pos] = (short)(pk23 >> 16);

    // issue NEXT step's scalar gathers into the now-dead acc regs (stay in
    // flight across the raw barrier; no vmcnt drain).
#pragma unroll
    for (int r = 0; r < 4; ++r) {
      const int ch = (cc >> (8 * r)) & 127;
      const float* pa = xpd + (ch << 9);
      acc[0][r] = pa[0];
      acc[1][r] = pa[128];
      acc[2][r] = pa[256];
      acc[3][r] = pa[384];
    }
    if (t + 2 < maxlen) {
      const int t3 = dir ? (maxlen - 3 - t) : (t + 2);
      cc = *(const u32*)(idx_s + t3 * N_WORDS + wbase);
    }
  }

  asm volatile("s_waitcnt lgkmcnt(0)" ::: "memory");
  __builtin_amdgcn_s_barrier();
}

// ---------------------------------------------------------------------------
// recurrence, PERSISTENT: 512 blocks x 512 thr; [0,256)=dir0, [256,512)=dir1.
// Block b handles tiles {b, 511-b, 512+b, 1023-b} (descending sort -> LPT).
// W_hh frags resident (64 AGPRs). Uniform-length tiles (most, after the sort)
// take a mask-free fast path. t=0 skips ds_read+MFMA (h=0); final step skips
// the h store.
//   A-frag: lane l reads k = kt*32 + (l>>4)*4 + j (j<4), +16 for j>=4
//   C/D   : lane l, reg r -> row m=(l>>4)*4+r, col n=l&15
// Pre-activations pre-scaled by -log2e (i,f,o) / -2log2e (g):
//   sigmoid(z) = rcp(1+exp2(zs)), tanh(z) = 2*rcp(1+exp2(zs)) - 1.
// ---------------------------------------------------------------------------
__global__ __launch_bounds__(512, 4) void k_lstm(
    const float* __restrict__ xp, const unsigned char* __restrict__ idx_s,
    const int* __restrict__ perm, const int* __restrict__ len_perm,
    const s16x8* __restrict__ wfrag, float* __restrict__ out) {
  const int dir = blockIdx.x >> 8;
  const int db  = blockIdx.x & 255;
  const int ug  = threadIdx.x >> 6;
  const int lane = threadIdx.x & 63;
  const int l15 = lane & 15, q = lane >> 4;
  const int u = ug * 16 + l15;

  s16x8 Bf[16];                                  // [g*4+kt], lives in AGPRs
  const s16x8* wb = wfrag + (dir * 8 + ug) * (16 * 64) + lane;
#pragma unroll
  for (int f = 0; f < 16; ++f) Bf[f] = wb[f * 64];

  __shared__ short hbuf[2][16 * HSTRIDE];
  const float* __restrict__ xpd = xp + (dir << 16) + u;
  const int pos = (ug >> 1) * 32 + (l15 >> 2) * 8 + (ug & 1) * 4 + (l15 & 3);

#pragma unroll 1
  for (int p = 0; p < 4; ++p) {
    const int rank = (p == 0) ? db : (p == 1) ? (511 - db)
                   : (p == 2) ? (512 + db) : (1023 - db);
    const int n0 = rank << 4;
    const int wbase = n0 + q * 4;
    const i32x4 lenv = *(const i32x4*)(len_perm + wbase);
    const int maxlen = len_perm[n0];             // slot n0 = longest in tile
    const bool unif = __all((lenv[0] == maxlen) & (lenv[1] == maxlen) &
                            (lenv[2] == maxlen) & (lenv[3] == maxlen));
    f32x4 h = (f32x4)0.0f, cs = (f32x4)0.0f;

    // prologue: gather step-0 gates; prefetch step-1 chars
    u32 cc = *(const u32*)(idx_s + (dir ? (maxlen - 1) : 0) * N_WORDS + wbase);
    f32x4 acc[4];
#pragma unroll
    for (int r = 0; r < 4; ++r) {
      const int ch = (cc >> (8 * r)) & 127;
      const float* pa = xpd + (ch << 9);
      acc[0][r] = pa[0];
      acc[1][r] = pa[128];
      acc[2][r] = pa[256];
      acc[3][r] = pa[384];
    }
    if (maxlen > 1)
      cc = *(const u32*)(idx_s + (dir ? (maxlen - 2) : 1) * N_WORDS + wbase);

    if (unif) {
#pragma unroll 1
      for (int t = 0; t < maxlen; ++t)
        lstm_step<true>(t, maxlen, dir, lenv, xpd, idx_s, wbase, cc, acc, h, cs,
                        Bf, hbuf, l15, q, pos);
    } else {
#pragma unroll 1
      for (int t = 0; t < maxlen; ++t)
        lstm_step<false>(t, maxlen, dir, lenv, xpd, idx_s, wbase, cc, acc, h, cs,
                         Bf, hbuf, l15, q, pos);
    }

    const i32x4 pw = *(const i32x4*)(perm + wbase);
#pragma unroll
    for (int r = 0; r < 4; ++r)
      out[(size_t)pw[r] * 256 + dir * HIDDEN + u] = h[r];
  }
}

// ---------------------------------------------------------------------------
extern "C" void kernel_launch(void* const* d_in, const int* in_sizes, int n_in,
                              void* d_out, int out_size, void* d_ws, size_t ws_size,
                              hipStream_t stream) {
  const float* x      = (const float*)d_in[0];
  const int*   lens   = (const int*)d_in[1];
  const float* W_ih_f = (const float*)d_in[2];
  const float* W_hh_f = (const float*)d_in[3];
  const float* b_ih_f = (const float*)d_in[4];
  const float* b_hh_f = (const float*)d_in[5];
  const float* W_ih_b = (const float*)d_in[6];
  const float* W_hh_b = (const float*)d_in[7];
  const float* b_ih_b = (const float*)d_in[8];
  const float* b_hh_b = (const float*)d_in[9];
  float* out = (float*)d_out;

  unsigned char* idx_w = (unsigned char*)d_ws + WS_IDXW;
  unsigned char* idx_s = (unsigned char*)d_ws + WS_IDXS;
  float* xp      = (float*)((char*)d_ws + WS_XPROJ);
  int*   perm    = (int*)((char*)d_ws + WS_PERM);
  int*   lenp    = (int*)((char*)d_ws + WS_LEN);
  int*   ghist   = (int*)((char*)d_ws + WS_CTRL);
  int*   gcursor = ghist + 32;
  s16x8* wfrag   = (s16x8*)((char*)d_ws + WS_WFRAG);

  hipMemsetAsync((char*)d_ws + WS_CTRL, 0, 192, stream);
  hipLaunchKernelGGL(k_front, dim3(NB_EXT + 640), dim3(256), 0, stream,
                     x, lens,
                     W_ih_f, b_ih_f, b_hh_f, W_ih_b, b_ih_b, b_hh_b,
                     W_hh_f, W_hh_b, xp, wfrag, idx_w, ghist);
  hipLaunchKernelGGL(k_place, dim3(N_WORDS / 256), dim3(256), 0, stream,
                     lens, ghist, gcursor, perm, lenp, idx_w, idx_s);
  hipLaunchKernelGGL(k_lstm, dim3(512), dim3(512), 0, stream,
                     xp, idx_s, perm, lenp, wfrag, out);
}